// Round 4
// baseline (753.586 us; speedup 1.0000x reference)
//
#include <hip/hip_runtime.h>
#include <cstdint>

#define C_DIM 256
#define EPS 1e-5f

typedef __attribute__((ext_vector_type(8))) short short8;
typedef __attribute__((ext_vector_type(4))) float f32x4;

__device__ __forceinline__ ushort f2bf(float f) {
  uint32_t u = __float_as_uint(f);
  u = (u + 0x7fffu + ((u >> 16) & 1u)) >> 16;
  return (ushort)u;
}
__device__ __forceinline__ float bflo(uint32_t p) { return __uint_as_float(p << 16); }
__device__ __forceinline__ float bfhi(uint32_t p) { return __uint_as_float(p & 0xffff0000u); }

// ---------------- setup kernels ----------------
__global__ void k_count(const int* __restrict__ col, int E, int* cnt) {
  int e = blockIdx.x * blockDim.x + threadIdx.x;
  if (e < E) atomicAdd(&cnt[col[e]], 1);
}

// reads cnt -> isd, then zeroes cnt so it can be reused as the fill cursor
__global__ void k_isd(int* cnt, float* isd, int n) {
  int i = blockIdx.x * blockDim.x + threadIdx.x;
  if (i < n) { isd[i] = rsqrtf((float)(cnt[i] + 1)); cnt[i] = 0; }
}

__global__ void k_scan1(const int* __restrict__ cnt, int* excl, int* bsum, int n) {
  __shared__ int s[1024];
  int i = blockIdx.x * 1024 + threadIdx.x;
  int v = (i < n) ? cnt[i] : 0;
  s[threadIdx.x] = v;
  __syncthreads();
  for (int off = 1; off < 1024; off <<= 1) {
    int t = (threadIdx.x >= off) ? s[threadIdx.x - off] : 0;
    __syncthreads();
    s[threadIdx.x] += t;
    __syncthreads();
  }
  if (i < n) excl[i] = s[threadIdx.x] - v;
  if (threadIdx.x == 1023) bsum[blockIdx.x] = s[1023];
}

__global__ void k_scan2(int* bsum, int nb) {
  __shared__ int s[1024];
  int v = (threadIdx.x < nb) ? bsum[threadIdx.x] : 0;
  s[threadIdx.x] = v;
  __syncthreads();
  for (int off = 1; off < 1024; off <<= 1) {
    int t = (threadIdx.x >= off) ? s[threadIdx.x - off] : 0;
    __syncthreads();
    s[threadIdx.x] += t;
    __syncthreads();
  }
  if (threadIdx.x < nb) bsum[threadIdx.x] = s[threadIdx.x] - v;
}

__global__ void k_scan3(int* excl, const int* __restrict__ bsum, int n, int E) {
  int i = blockIdx.x * 1024 + threadIdx.x;
  if (i < n) excl[i] += bsum[blockIdx.x];
  if (i == 0) excl[n] = E;
}

// packed edge record: .x = src node, .y = fp32 bits of norm
__global__ void k_fill(const int* __restrict__ row, const int* __restrict__ col, int E,
                       const int* __restrict__ row_ptr, int* cursor,
                       const float* __restrict__ isd, int2* __restrict__ edat) {
  int e = blockIdx.x * blockDim.x + threadIdx.x;
  if (e < E) {
    int d = col[e], s = row[e];
    int p = row_ptr[d] + atomicAdd(&cursor[d], 1);
    edat[p] = make_int2(s, __float_as_int(isd[s] * isd[d]));
  }
}

__global__ void k_cvt_x(const float* __restrict__ x, ushort* __restrict__ xb, int n4) {
  int i = blockIdx.x * blockDim.x + threadIdx.x;
  if (i < n4) {
    float4 v = ((const float4*)x)[i];
    ushort4 o;
    o.x = f2bf(v.x); o.y = f2bf(v.y); o.z = f2bf(v.z); o.w = f2bf(v.w);
    ((ushort4*)xb)[i] = o;
  }
}

// W [K][N] fp32 -> Wt [N][K] bf16, for both layer weights
__global__ void k_cvt_w(const float* __restrict__ W1, const float* __restrict__ W2,
                        ushort* __restrict__ Wt1, ushort* __restrict__ Wt2) {
  int i = blockIdx.x * blockDim.x + threadIdx.x;  // output index [n][k]
  int n = i >> 8, k = i & 255;
  Wt1[i] = f2bf(W1[k * 256 + n]);
  Wt2[i] = f2bf(W2[k * 256 + n]);
}

// ---------------- bf16 MFMA GEMM: Cb[M,256] = A[M,256] @ Wt^T ----------------
__global__ __launch_bounds__(256) void k_gemm_bf16(const ushort* __restrict__ A,
                                                   const ushort* __restrict__ Wt,
                                                   ushort* __restrict__ Cb, int M) {
  __shared__ ushort As[128 * 64];
  __shared__ ushort Bs[128 * 64];
  const int tid = threadIdx.x;
  const int wave = tid >> 6, lane = tid & 63;
  const int bm = blockIdx.x * 128;
  const int bn = blockIdx.y * 128;
  const int wm = (wave >> 1) * 64, wn = (wave & 1) * 64;

  f32x4 acc[4][4] = {};

  const int r_off = lane >> 3;  // 0..7 rows per 1KB staging inst
  const int cc = lane & 7;      // 16B chunk slot within row

  for (int k0 = 0; k0 < C_DIM; k0 += 64) {
#pragma unroll
    for (int j = 0; j < 4; j++) {
      int rl = wave * 32 + j * 8 + r_off;  // tile row 0..127
      int c = cc ^ (rl & 7);               // swizzled source chunk
      int gm = bm + rl; if (gm >= M) gm = M - 1;
      const ushort* ga = &A[(size_t)gm * C_DIM + k0 + c * 8];
      ushort* la = &As[(size_t)(wave * 32 + j * 8) * 64];
      __builtin_amdgcn_global_load_lds((const __attribute__((address_space(1))) void*)ga,
                                       (__attribute__((address_space(3))) void*)la, 16, 0, 0);
      const ushort* gb = &Wt[(size_t)(bn + rl) * C_DIM + k0 + c * 8];
      ushort* lb = &Bs[(size_t)(wave * 32 + j * 8) * 64];
      __builtin_amdgcn_global_load_lds((const __attribute__((address_space(1))) void*)gb,
                                       (__attribute__((address_space(3))) void*)lb, 16, 0, 0);
    }
    __syncthreads();
#pragma unroll
    for (int s = 0; s < 2; s++) {
      short8 af[4], bfr[4];
#pragma unroll
      for (int t = 0; t < 4; t++) {
        int ra = wm + t * 16 + (lane & 15);
        int ca = s * 4 + (lane >> 4);
        af[t] = *(const short8*)&As[ra * 64 + ((ca ^ (ra & 7)) << 3)];
        int rb = wn + t * 16 + (lane & 15);
        bfr[t] = *(const short8*)&Bs[rb * 64 + ((ca ^ (rb & 7)) << 3)];
      }
#pragma unroll
      for (int mt = 0; mt < 4; mt++)
#pragma unroll
        for (int nt = 0; nt < 4; nt++)
          acc[mt][nt] = __builtin_amdgcn_mfma_f32_16x16x32_bf16(af[mt], bfr[nt], acc[mt][nt], 0, 0, 0);
    }
    __syncthreads();
  }

  // epilogue: C/D layout col=lane&15, row=(lane>>4)*4+reg (m89-verified)
#pragma unroll
  for (int mt = 0; mt < 4; mt++) {
#pragma unroll
    for (int nt = 0; nt < 4; nt++) {
      int col = bn + wn + nt * 16 + (lane & 15);
      int row0 = bm + wm + mt * 16 + ((lane >> 4) << 2);
#pragma unroll
      for (int r = 0; r < 4; r++) {
        int row = row0 + r;
        if (row < M) Cb[(size_t)row * C_DIM + col] = f2bf(acc[mt][nt][r]);
      }
    }
  }
}

// ---------------- fused aggregate(bf16 gather) + bias + LN + ReLU ----------------
// 8-deep gather groups; masked tail (index clamped to e0, weight zeroed) so the
// remainder still issues 8 parallel row loads instead of a serial 1-deep tail.
__global__ __launch_bounds__(256) void k_agg_ln(const ushort* __restrict__ xwb,
    const int2* __restrict__ edat, const int* __restrict__ row_ptr,
    const float* __restrict__ isd,
    const float* __restrict__ bias, const float* __restrict__ gamma,
    const float* __restrict__ beta, float* __restrict__ out,
    ushort* __restrict__ outb, int n) {
  int i = blockIdx.x * 4 + (threadIdx.x >> 6);
  int lane = threadIdx.x & 63;
  if (i >= n) return;
  const uint2* xw2 = (const uint2*)xwb;  // 8B = 4 bf16 channels per lane

  float si = isd[i];
  float sn = si * si;
  uint2 p = xw2[(size_t)i * 64 + lane];
  float a0 = bflo(p.x) * sn, a1 = bfhi(p.x) * sn;
  float a2 = bflo(p.y) * sn, a3 = bfhi(p.y) * sn;

  int e0 = row_ptr[i], e1 = row_ptr[i + 1];
  for (int e = e0; e < e1; e += 8) {
    int idx[8]; float w[8];
#pragma unroll
    for (int j = 0; j < 8; j++) {
      int ee = e + j;
      bool ok = ee < e1;
      int2 ed = edat[ok ? ee : e0];
      idx[j] = ed.x;
      w[j] = ok ? __int_as_float(ed.y) : 0.0f;
    }
    uint2 v[8];
#pragma unroll
    for (int j = 0; j < 8; j++) v[j] = xw2[(size_t)idx[j] * 64 + lane];
#pragma unroll
    for (int j = 0; j < 8; j++) {
      a0 += bflo(v[j].x) * w[j];
      a1 += bfhi(v[j].x) * w[j];
      a2 += bflo(v[j].y) * w[j];
      a3 += bfhi(v[j].y) * w[j];
    }
  }

  float4 bv = ((const float4*)bias)[lane];
  a0 += bv.x; a1 += bv.y; a2 += bv.z; a3 += bv.w;

  float sum = a0 + a1 + a2 + a3;
  float sq = a0 * a0 + a1 * a1 + a2 * a2 + a3 * a3;
#pragma unroll
  for (int off = 32; off >= 1; off >>= 1) {
    sum += __shfl_xor(sum, off, 64);
    sq += __shfl_xor(sq, off, 64);
  }
  float mu = sum * (1.0f / C_DIM);
  float var = sq * (1.0f / C_DIM) - mu * mu;
  float rs = rsqrtf(var + EPS);

  float4 g = ((const float4*)gamma)[lane];
  float4 bt = ((const float4*)beta)[lane];
  float4 o;
  o.x = fmaxf((a0 - mu) * rs * g.x + bt.x, 0.0f);
  o.y = fmaxf((a1 - mu) * rs * g.y + bt.y, 0.0f);
  o.z = fmaxf((a2 - mu) * rs * g.z + bt.z, 0.0f);
  o.w = fmaxf((a3 - mu) * rs * g.w + bt.w, 0.0f);
  ((float4*)out)[(size_t)i * 64 + lane] = o;

  if (outb) {  // bf16 copy feeding next layer's GEMM
    uint2 q;
    q.x = (uint32_t)f2bf(o.x) | ((uint32_t)f2bf(o.y) << 16);
    q.y = (uint32_t)f2bf(o.z) | ((uint32_t)f2bf(o.w) << 16);
    ((uint2*)outb)[(size_t)i * 64 + lane] = q;
  }
}

// ---------------- host ----------------
extern "C" void kernel_launch(void* const* d_in, const int* in_sizes, int n_in,
                              void* d_out, int out_size, void* d_ws, size_t ws_size,
                              hipStream_t stream) {
  const float* x = (const float*)d_in[0];
  const int* edges = (const int*)d_in[1];
  const float* W1 = (const float*)d_in[2];
  const float* b1 = (const float*)d_in[3];
  const float* W2 = (const float*)d_in[4];
  const float* b2 = (const float*)d_in[5];
  const float* gamma = (const float*)d_in[6];
  const float* beta = (const float*)d_in[7];

  int N = in_sizes[0] / C_DIM;
  int E = in_sizes[1] / 2;
  const int* row = edges;
  const int* col = edges + E;

  char* ws = (char*)d_ws;
  size_t off = 0;
  auto alloc = [&](size_t bytes) -> void* {
    void* p = ws + off;
    off = (off + bytes + 255) & ~(size_t)255;
    return p;
  };
  ushort* xwb = (ushort*)alloc((size_t)N * C_DIM * 2);  // GEMM output, bf16
  ushort* xb  = (ushort*)alloc((size_t)N * C_DIM * 2);  // layer-1 A; aliased as z1-bf16 after agg1
  ushort* Wt1 = (ushort*)alloc(65536 * 2);
  ushort* Wt2 = (ushort*)alloc(65536 * 2);
  int* cnt = (int*)alloc((size_t)N * 4);                 // reused as fill cursor
  float* isd = (float*)alloc((size_t)N * 4);
  int* row_ptr = (int*)alloc((size_t)(N + 1) * 4);
  int nb = (N + 1023) / 1024;
  int* bsum = (int*)alloc((size_t)nb * 4);
  int2* edat = (int2*)alloc((size_t)E * 8);              // packed (src, nrm)

  float* z1 = (float*)d_out;
  float* z2 = (float*)d_out + (size_t)N * C_DIM;

  // conversions
  int n4 = N * C_DIM / 4;
  k_cvt_x<<<(n4 + 255) / 256, 256, 0, stream>>>(x, xb, n4);
  k_cvt_w<<<256, 256, 0, stream>>>(W1, W2, Wt1, Wt2);

  // CSR build (shared by both layers)
  hipMemsetAsync(cnt, 0, (size_t)N * 4, stream);
  k_count<<<(E + 255) / 256, 256, 0, stream>>>(col, E, cnt);
  k_scan1<<<nb, 1024, 0, stream>>>(cnt, row_ptr, bsum, N);
  k_scan2<<<1, 1024, 0, stream>>>(bsum, nb);
  k_scan3<<<nb, 1024, 0, stream>>>(row_ptr, bsum, N, E);
  k_isd<<<(N + 255) / 256, 256, 0, stream>>>(cnt, isd, N);  // zeroes cnt -> cursor
  k_fill<<<(E + 255) / 256, 256, 0, stream>>>(row, col, E, row_ptr, cnt, isd, edat);

  dim3 ggrid((N + 127) / 128, 2);
  int agg_blocks = (N + 3) / 4;

  // layer 1
  k_gemm_bf16<<<ggrid, 256, 0, stream>>>(xb, Wt1, xwb, N);
  k_agg_ln<<<agg_blocks, 256, 0, stream>>>(xwb, edat, row_ptr, isd, b1, gamma, beta, z1, xb, N);
  // layer 2 (xb now holds z1 in bf16)
  k_gemm_bf16<<<ggrid, 256, 0, stream>>>(xb, Wt2, xwb, N);
  k_agg_ln<<<agg_blocks, 256, 0, stream>>>(xwb, edat, row_ptr, isd, b2, gamma, beta, z2, nullptr, N);
}